// Round 2
// baseline (1584.190 us; speedup 1.0000x reference)
//
#include <hip/hip_runtime.h>

// Shifted 3x3 VALID conv: out[n][o][x][y] = bias[o] +
//   sum_{c,i,j} inp[n][c][wrap(x+i-1)][y+j] * filt[o][c][i][j]
// B=8, Cin=Cout=8, H=W=1024, OH=OW=1022, fp32.
//
// R4: back to LDS staging (R3 post-mortem: direct-global tripled VALU time -
// overlapping 12B/lane windows defeat wide loads and re-read every value 3x;
// LDS is the instruction-minimal path). R2's limiter was phase herding:
// stage -> vmcnt(0) -> barrier -> compute once per block serialized memory
// and VALU bursts (VALU 52% + HBM 34%, neither saturated). R4 pipelines:
// channel-PAIR double-buffered LDS, stage loads issued BEFORE compute,
// LDS writes + vmcnt AFTER (T14 split), barrier per phase. RPT 2->4 halves
// LDS-read pressure per FMA (18 ds_read per channel for 4 output rows).

#define H     1024
#define W     1024
#define OH    1022
#define OW    1022
#define CIN   8
#define COUT  8

#define TY    64                 // output cols per block (= lanes)
#define TX    16                 // output rows per block
#define RPT   4                  // output rows per thread
#define NTG   (TX / RPT)         // 4 row-groups (waves)
#define NTHREADS (TY * NTG)      // 256
#define ROWS  (TX + 2)           // 18 input rows staged
#define COLS  68                 // 66 needed, padded for float4 staging
#define NCHK  (COLS / 4)         // 17 float4 chunks per row
#define CPAIR 2                  // channels staged per phase
#define NPH   (CIN / CPAIR)      // 4 phases
#define CHUNKS (CPAIR * ROWS * NCHK)               // 612 float4 per phase
#define SITER  ((CHUNKS + NTHREADS - 1) / NTHREADS) // 3 chunks/thread

__global__ __launch_bounds__(NTHREADS, 6)
void conv_roll_kernel(const float* __restrict__ inp,
                      const float* __restrict__ filt,
                      const float* __restrict__ bias,
                      float* __restrict__ out) {
    __shared__ float s_in[2][CPAIR][ROWS][COLS];   // 2*2*18*68*4 = 19.6 KB

    const int tid    = threadIdx.x;
    const int ty     = tid & 63;
    const int tg     = tid >> 6;        // 0..3
    const int n      = blockIdx.z;
    const int x_base = blockIdx.y * TX;
    const int y_base = blockIdx.x * TY;

    // ---- Per-thread staging descriptors (computed once, reused all phases) ----
    const float* __restrict__ inp_n = inp + ((size_t)n * CIN * H * W);
    const float* gp[SITER];
    int  lofs[SITER];
    bool act[SITER];
#pragma unroll
    for (int k = 0; k < SITER; ++k) {
        const int idx = tid + k * NTHREADS;
        act[k] = (idx < CHUNKS);
        const int i2  = act[k] ? idx : 0;
        const int c   = i2 / (ROWS * NCHK);
        const int rem = i2 - c * (ROWS * NCHK);
        const int r   = rem / NCHK;
        const int col = (rem - r * NCHK) * 4;

        int gr = x_base + r - 1;                 // -1 .. 1024
        gr = (gr < 0) ? (H - 1) : ((gr > H - 1) ? (H - 1) : gr);  // wrap / clamp(dead)
        int gc = y_base + col;
        if (gc > W - 4) gc = W - 4;              // clamped chunks feed guarded outputs only

        gp[k]   = inp_n + ((size_t)c * H + gr) * W + gc;
        lofs[k] = (c * ROWS + r) * COLS + col;   // float index within one buffer
    }

    auto stage_load = [&](float4 (&v)[SITER]) {
#pragma unroll
        for (int k = 0; k < SITER; ++k) {
            if (act[k]) v[k] = *(const float4*)gp[k];
            gp[k] += (size_t)CPAIR * H * W;      // advance to next channel pair
        }
    };
    auto stage_write = [&](int buf, const float4 (&v)[SITER]) {
        float* sb = &s_in[buf][0][0][0];
#pragma unroll
        for (int k = 0; k < SITER; ++k)
            if (act[k]) *(float4*)(sb + lofs[k]) = v[k];
    };

    // ---- Accumulators ----
    const int r0 = tg * RPT;                     // local row base (tile row 0 == x_base-1)
    float acc[RPT][COUT];
#pragma unroll
    for (int o = 0; o < COUT; ++o) {
        const float bv = bias[o];                // uniform -> s_load
#pragma unroll
        for (int u = 0; u < RPT; ++u) acc[u][o] = bv;
    }

    auto compute = [&](int buf, int p) {
#pragma unroll
        for (int cc = 0; cc < CPAIR; ++cc) {
            float win[RPT + 2][3];
#pragma unroll
            for (int r = 0; r < RPT + 2; ++r)
#pragma unroll
                for (int j = 0; j < 3; ++j)
                    win[r][j] = s_in[buf][cc][r0 + r][ty + j];

            const int c = p * CPAIR + cc;
#pragma unroll
            for (int i = 0; i < 3; ++i)
#pragma unroll
                for (int j = 0; j < 3; ++j)
#pragma unroll
                    for (int o = 0; o < COUT; ++o) {
                        const float fv = filt[((o * CIN + c) * 3 + i) * 3 + j]; // uniform
#pragma unroll
                        for (int u = 0; u < RPT; ++u)
                            acc[u][o] += win[u + i][j] * fv;
                    }
        }
    };

    // ---- Pipelined phases: load(p+1) -> compute(p) -> write(p+1) -> barrier ----
    {
        float4 v0[SITER];
        stage_load(v0);                 // pair 0
        stage_write(0, v0);
    }
    __syncthreads();

#pragma unroll
    for (int p = 0; p < NPH - 1; ++p) {
        float4 v[SITER];
        stage_load(v);                  // pair p+1 in flight under compute
        compute(p & 1, p);
        stage_write((p + 1) & 1, v);    // vmcnt wait lands here, after compute
        __syncthreads();
    }
    compute((NPH - 1) & 1, NPH - 1);

    // ---- Store (coalesced across lanes per o-plane) ----
    const int yc = y_base + ty;
    if (yc < OW) {
#pragma unroll
        for (int u = 0; u < RPT; ++u) {
            const int xr = x_base + r0 + u;
            if (xr < OH) {
#pragma unroll
                for (int o = 0; o < COUT; ++o)
                    out[(((size_t)(n * COUT + o)) * OH + xr) * OW + yc] = acc[u][o];
            }
        }
    }
}

extern "C" void kernel_launch(void* const* d_in, const int* in_sizes, int n_in,
                              void* d_out, int out_size, void* d_ws, size_t ws_size,
                              hipStream_t stream) {
    const float* inp  = (const float*)d_in[0];
    const float* filt = (const float*)d_in[1];
    const float* bias = (const float*)d_in[2];
    float* out = (float*)d_out;

    dim3 grid((OW + TY - 1) / TY,   // 16 y-tiles
              (OH + TX - 1) / TX,   // 64 x-tiles
              8);                   // batch
    conv_roll_kernel<<<grid, dim3(NTHREADS), 0, stream>>>(inp, filt, bias, out);
}